// Round 1
// baseline (22510.504 us; speedup 1.0000x reference)
//
#include <hip/hip_runtime.h>
#include <hip/hip_bf16.h>
#include <cstddef>

// Problem constants (from reference): B=64, T=512, D=1024, H=1024
#define BATCH 64
#define TT    512
#define DD    1024
#define HH    1024

// ---------------- Kernel A: xp = x @ Wx + bias, written into d_out ----------
// M = B*T = 32768, N = H = 1024, K = D = 1024. All row-major fp32.
#define BM 64
#define BN 64
#define BK 16
#define TM 4
#define TN 4

__global__ __launch_bounds__(256) void gemm_xp(
    const float* __restrict__ A,    // [M, K] = x
    const float* __restrict__ Bw,   // [K, N] = Wx
    const float* __restrict__ bias, // [N]
    float* __restrict__ C)          // [M, N] -> xp (into d_out)
{
    const int M = BATCH * TT;
    const int N = HH;
    const int K = DD;

    __shared__ float As[BK][BM + 1]; // transposed store, pad to dodge conflicts
    __shared__ float Bs[BK][BN];

    const int tid  = threadIdx.x;
    const int brow = blockIdx.y * BM;
    const int bcol = blockIdx.x * BN;

    const int tcol = (tid % 16) * TN;
    const int trow = (tid / 16) * TM;

    float acc[TM][TN];
#pragma unroll
    for (int m = 0; m < TM; ++m)
#pragma unroll
        for (int n = 0; n < TN; ++n) acc[m][n] = 0.f;

    for (int k0 = 0; k0 < K; k0 += BK) {
        // Load A tile: BM x BK (store transposed As[c][r])
#pragma unroll
        for (int i = tid; i < BM * BK; i += 256) {
            int r = i / BK, c = i % BK;
            As[c][r] = A[(size_t)(brow + r) * K + (k0 + c)];
        }
        // Load B tile: BK x BN
#pragma unroll
        for (int i = tid; i < BK * BN; i += 256) {
            int r = i / BN, c = i % BN;
            Bs[r][c] = Bw[(size_t)(k0 + r) * N + (bcol + c)];
        }
        __syncthreads();

#pragma unroll
        for (int k = 0; k < BK; ++k) {
            float a[TM], bv[TN];
#pragma unroll
            for (int m = 0; m < TM; ++m) a[m] = As[k][trow + m];
#pragma unroll
            for (int n = 0; n < TN; ++n) bv[n] = Bs[k][tcol + n];
#pragma unroll
            for (int m = 0; m < TM; ++m)
#pragma unroll
                for (int n = 0; n < TN; ++n) acc[m][n] += a[m] * bv[n];
        }
        __syncthreads();
    }

#pragma unroll
    for (int m = 0; m < TM; ++m) {
        size_t row = (size_t)(brow + trow + m) * N;
#pragma unroll
        for (int n = 0; n < TN; ++n) {
            int col = bcol + tcol + n;
            C[row + col] = acc[m][n] + bias[col];
        }
    }
}

// ---------------- Kernel B: sequential scan, one workgroup per batch --------
// h_t = tanh(xp_t + h_{t-1} @ Wh). xp lives in `out` and is overwritten by h.
// Thread j owns output column j. h kept in LDS (broadcast reads).
__global__ __launch_bounds__(1024) void rnn_scan(
    const float* __restrict__ Wh,  // [H, H] row-major
    float* __restrict__ out)       // [B, T, H]; holds xp on entry
{
    __shared__ float hbuf[HH];

    const int b = blockIdx.x;
    const int j = threadIdx.x;

    hbuf[j] = 0.f;
    __syncthreads();

    float* rowbase = out + (size_t)b * TT * HH;

    for (int t = 0; t < TT; ++t) {
        float acc = rowbase[(size_t)t * HH + j];

        // acc += sum_i h[i] * Wh[i][j]   (coalesced over j; LDS broadcast on h)
#pragma unroll 1
        for (int i = 0; i < HH; i += 8) {
#pragma unroll
            for (int u = 0; u < 8; ++u) {
                acc += hbuf[i + u] * Wh[(size_t)(i + u) * HH + j];
            }
        }

        float hn = tanhf(acc);
        __syncthreads();          // everyone done reading old h
        hbuf[j] = hn;
        rowbase[(size_t)t * HH + j] = hn;
        __syncthreads();          // new h visible before next step
    }
}

extern "C" void kernel_launch(void* const* d_in, const int* in_sizes, int n_in,
                              void* d_out, int out_size, void* d_ws, size_t ws_size,
                              hipStream_t stream) {
    const float* x    = (const float*)d_in[0]; // [B, T, D]
    const float* Wx   = (const float*)d_in[1]; // [D, H]
    const float* Wh   = (const float*)d_in[2]; // [H, H]
    const float* bias = (const float*)d_in[3]; // [H]

    float* out = (float*)d_out; // [B, T, H]

    // Kernel A: xp = x @ Wx + bias  -> into d_out
    dim3 gridA(HH / BN, (BATCH * TT) / BM);
    gemm_xp<<<gridA, 256, 0, stream>>>(x, Wx, bias, out);

    // Kernel B: in-place scan over T, one block per batch
    rnn_scan<<<BATCH, HH, 0, stream>>>(Wh, out);
}

// Round 2
// 5202.558 us; speedup vs baseline: 4.3268x; 4.3268x over previous
//
#include <hip/hip_runtime.h>
#include <hip/hip_bf16.h>
#include <hip/hip_fp16.h>
#include <cstddef>

// Problem constants: B=64, T=512, D=1024, H=1024
#define BATCH 64
#define TT    512
#define DD    1024
#define HH    1024

typedef _Float16 f16x8 __attribute__((ext_vector_type(8)));
typedef float    f32x4 __attribute__((ext_vector_type(4)));

// ---------------- Kernel A: xp = x @ Wx + bias, written into d_out ----------
// (unchanged fp32 tile GEMM — known good; MFMA-ize next round)
#define BM 64
#define BN 64
#define BK 16
#define TM 4
#define TN 4

__global__ __launch_bounds__(256) void gemm_xp(
    const float* __restrict__ A,    // [M, K] = x
    const float* __restrict__ Bw,   // [K, N] = Wx
    const float* __restrict__ bias, // [N]
    float* __restrict__ C)          // [M, N] -> xp (into d_out)
{
    const int N = HH;
    const int K = DD;

    __shared__ float As[BK][BM + 1];
    __shared__ float Bs[BK][BN];

    const int tid  = threadIdx.x;
    const int brow = blockIdx.y * BM;
    const int bcol = blockIdx.x * BN;

    const int tcol = (tid % 16) * TN;
    const int trow = (tid / 16) * TM;

    float acc[TM][TN];
#pragma unroll
    for (int m = 0; m < TM; ++m)
#pragma unroll
        for (int n = 0; n < TN; ++n) acc[m][n] = 0.f;

    for (int k0 = 0; k0 < K; k0 += BK) {
#pragma unroll
        for (int i = tid; i < BM * BK; i += 256) {
            int r = i / BK, c = i % BK;
            As[c][r] = A[(size_t)(brow + r) * K + (k0 + c)];
        }
#pragma unroll
        for (int i = tid; i < BK * BN; i += 256) {
            int r = i / BN, c = i % BN;
            Bs[r][c] = Bw[(size_t)(k0 + r) * N + (bcol + c)];
        }
        __syncthreads();

#pragma unroll
        for (int k = 0; k < BK; ++k) {
            float a[TM], bv[TN];
#pragma unroll
            for (int m = 0; m < TM; ++m) a[m] = As[k][trow + m];
#pragma unroll
            for (int n = 0; n < TN; ++n) bv[n] = Bs[k][tcol + n];
#pragma unroll
            for (int m = 0; m < TM; ++m)
#pragma unroll
                for (int n = 0; n < TN; ++n) acc[m][n] += a[m] * bv[n];
        }
        __syncthreads();
    }

#pragma unroll
    for (int m = 0; m < TM; ++m) {
        size_t row = (size_t)(brow + trow + m) * N;
#pragma unroll
        for (int n = 0; n < TN; ++n) {
            int col = bcol + tcol + n;
            C[row + col] = acc[m][n] + bias[col];
        }
    }
}

// ---------------- Kernel B0: Wh f32 -> fp16, MFMA-B-fragment order ----------
// Frag order: Whf[(((cg*32 + kk)*64) + lane)*8 + e] = Wh[k][col]
//   where k = kk*32 + (lane>>4)*8 + e, col = cg*16 + (lane&15).
// Lane l of MFMA 16x16x32_f16 B-operand holds B[k = 8*(l>>4)+e + 32*kk][col = l&15]
// (8 consecutive k per lane — same layout the verified bf16 ladder uses with
//  one ds_read_b128 per fragment).
__global__ __launch_bounds__(256) void convert_whf(
    const float* __restrict__ Wh, _Float16* __restrict__ Whf)
{
    int tid = blockIdx.x * 256 + threadIdx.x;   // tid = k*1024 + col (1M threads)
    int k   = tid >> 10;
    int col = tid & 1023;
    float v = Wh[tid];                          // coalesced read
    int cg   = col >> 4;
    int kk   = k >> 5;
    int lane = ((k >> 3) & 3) * 16 + (col & 15);
    int e    = k & 7;
    Whf[((size_t)(cg * 32 + kk) * 64 + lane) * 8 + e] = (_Float16)v; // scattered 2B write
}

// ---------------- Kernel B: one recurrence step (launch = barrier) ----------
// Grid 64 blocks (one per 16-col group), 256 threads = 4 waves (one per
// 16-batch group). Wave computes the 16x16 tile h_new[bg,cg] via 32 chained
// MFMA f32_16x16x32_f16 over K=1024, adds xp (in-place in d_out), tanh,
// stores fp32 to out and fp16 to the h double buffer.
__global__ __launch_bounds__(256) void rnn_step(
    const _Float16* __restrict__ Whf,   // frag-ordered [64][32][64][8]
    const _Float16* __restrict__ hprev, // [64][1024] fp16 (t-1)
    _Float16* __restrict__ hnext,       // [64][1024] fp16 (t)
    float* __restrict__ out,            // [64][512][1024]; xp -> h in place
    int t)
{
    const int cg   = blockIdx.x;        // 0..63 col group
    const int bg   = threadIdx.x >> 6;  // 0..3  batch group (wave id)
    const int lane = threadIdx.x & 63;
    const int l15  = lane & 15;
    const int lq   = lane >> 4;

    f32x4 acc = {0.f, 0.f, 0.f, 0.f};

    if (t > 0) {
        // B frags: perfectly coalesced 16B/lane loads, L2-resident slice
        const f16x8* wp = (const f16x8*)Whf + ((size_t)cg * 32 * 64 + lane);
        // A frags: lane holds h_prev[bg*16 + (l&15)][kk*32 + (l>>4)*8 .. +7]
        const _Float16* ap = hprev + (size_t)(bg * 16 + l15) * HH + lq * 8;
#pragma unroll
        for (int kk = 0; kk < 32; ++kk) {
            f16x8 a = *(const f16x8*)(ap + (size_t)kk * 32);
            acc = __builtin_amdgcn_mfma_f32_16x16x32_f16(a, wp[(size_t)kk * 64], acc, 0, 0, 0);
        }
    }

    const int col = cg * 16 + l15;
#pragma unroll
    for (int v = 0; v < 4; ++v) {
        int b = bg * 16 + lq * 4 + v;   // C/D layout: row = 4*(l>>4)+v, col = l&15
        size_t o = ((size_t)b * TT + t) * HH + col;
        float hv = tanhf(acc[v] + out[o]);
        out[o] = hv;
        hnext[(size_t)b * HH + col] = (_Float16)hv;
    }
}

extern "C" void kernel_launch(void* const* d_in, const int* in_sizes, int n_in,
                              void* d_out, int out_size, void* d_ws, size_t ws_size,
                              hipStream_t stream) {
    const float* x    = (const float*)d_in[0]; // [B, T, D]
    const float* Wx   = (const float*)d_in[1]; // [D, H]
    const float* Wh   = (const float*)d_in[2]; // [H, H]
    const float* bias = (const float*)d_in[3]; // [H]

    float* out = (float*)d_out;                // [B, T, H]

    // Workspace layout: Whf (1M halves = 2 MB) | hb0 (128 KB) | hb1 (128 KB)
    _Float16* Whf = (_Float16*)d_ws;
    _Float16* hb0 = Whf + (1u << 20);
    _Float16* hb1 = hb0 + BATCH * HH;

    // Wh -> fp16 frag order (1M threads)
    convert_whf<<<4096, 256, 0, stream>>>(Wh, Whf);

    // xp = x @ Wx + bias -> d_out
    dim3 gridA(HH / BN, (BATCH * TT) / BM);
    gemm_xp<<<gridA, 256, 0, stream>>>(x, Wx, bias, out);

    // t = 0: h = tanh(xp) (h0 = 0 -> no matvec; hprev unused)
    rnn_step<<<64, 256, 0, stream>>>(Whf, hb1, hb0, out, 0);

    // t = 1..511: launch boundary acts as the grid-wide barrier
    _Float16* hb[2] = {hb0, hb1};
    for (int t = 1; t < TT; ++t) {
        rnn_step<<<64, 256, 0, stream>>>(Whf, hb[(t + 1) & 1], hb[t & 1], out, t);
    }
}